// Round 4
// baseline (237.883 us; speedup 1.0000x reference)
//
#include <hip/hip_runtime.h>
#include <stdint.h>

#define Bb 8
#define Dd 256
#define Ll 4096
#define Kk 4096
#define Nn (Bb * Ll)          // 32768 rows
#define OUT0 (Bb * Dd * Ll)   // 8388608

typedef short short8 __attribute__((ext_vector_type(8)));
typedef float floatx4 __attribute__((ext_vector_type(4)));

__device__ __forceinline__ unsigned short f32_to_bf16(float f) {
    union { float f; uint32_t u; } v; v.f = f;
    return (unsigned short)((v.u + 0x7FFFu + ((v.u >> 16) & 1u)) >> 16);
}

// ---------------------------------------------------------------- kernel 1
// blocks 0..1023: codebook normalize -> bf16 (block 0 zeroes counts+lossacc)
// blocks 1024..1535: register transpose x [B,D,L]f32 -> A [B*L,D]bf16 (no LDS)
__global__ void k_prep(const float* __restrict__ x, const float* __restrict__ w,
                       unsigned short* __restrict__ A, unsigned short* __restrict__ wn,
                       int* __restrict__ counts) {
    int blk = blockIdx.x, tid = threadIdx.x;
    if (blk < 1024) {
        if (blk == 0)
            for (int i = tid; i < Kk + 1; i += 256) counts[i] = 0;
        int row  = blk * 4 + (tid >> 6);
        int lane = tid & 63;
        float4 v = ((const float4*)(w + (size_t)row * Dd))[lane];
        float ss = v.x*v.x + v.y*v.y + v.z*v.z + v.w*v.w;
#pragma unroll
        for (int m = 1; m < 64; m <<= 1) ss += __shfl_xor(ss, m, 64);
        float s = 1.0f / fmaxf(sqrtf(ss), 1e-12f);
        ushort4 o;
        o.x = f32_to_bf16(v.x*s); o.y = f32_to_bf16(v.y*s);
        o.z = f32_to_bf16(v.z*s); o.w = f32_to_bf16(v.w*s);
        ((ushort4*)(wn + (size_t)row * Dd))[lane] = o;
    } else {
        // 512 transpose blocks: 64 L x 256 D each.
        int t = blk - 1024;
        int b = t >> 6, l0 = (t & 63) * 64;
        int q = tid >> 4, dblk = tid & 15;   // l-quad, d-block of 16
        const float* src = x + ((size_t)b * Dd + dblk * 16) * Ll + l0 + q * 4;
        float4 f[16];
#pragma unroll
        for (int dd = 0; dd < 16; ++dd)
            f[dd] = *(const float4*)(src + (size_t)dd * Ll);
        unsigned short* dst = A + (size_t)(b * Ll + l0) * Dd;
#pragma unroll
        for (int jl = 0; jl < 4; ++jl) {
            unsigned short tmp[16];
#pragma unroll
            for (int dd = 0; dd < 16; ++dd)
                tmp[dd] = f32_to_bf16(((const float*)&f[dd])[jl]);
            unsigned short* o = dst + (size_t)(q * 4 + jl) * Dd + dblk * 16;
            *(short8*)(o)     = *(const short8*)(tmp);
            *(short8*)(o + 8) = *(const short8*)(tmp + 8);
        }
    }
}

// ---------------------------------------------------------------- kernel 2
// argmax_k <A_n, Wn_k>; A-frags in registers (full K=256); B streamed
// straight from L2 with a 2-slot register pipeline; packed-u32-key argmax
// (acc biased +192 -> positive one-binade floats; low 12 bits carry col idx).
__global__ __launch_bounds__(256, 2) void k_gemm_argmax(
        const unsigned short* __restrict__ A, const unsigned short* __restrict__ Wn,
        unsigned int* __restrict__ keys) {
    __shared__ unsigned int red[128][2];
    int blk = blockIdx.x;
    int cg = blk & 1, bm = blk >> 1;
    int tid = threadIdx.x, lane = tid & 63, w = tid >> 6;
    int wm = w >> 1, wn = w & 1;
    int l15 = lane & 15, l4 = lane >> 4;

    // A fragments: row = bm*128 + wm*64 + fm*16 + l15, k = kk*32 + l4*8
    const unsigned short* Arow = A + (size_t)(bm * 128 + wm * 64 + l15) * Dd + l4 * 8;
    short8 af[4][8];
#pragma unroll
    for (int fm = 0; fm < 4; ++fm)
#pragma unroll
        for (int kk = 0; kk < 8; ++kk)
            af[fm][kk] = *(const short8*)(Arow + fm * 16 * Dd + kk * 32);

    // B lane base: row (= C col) = cg*2048 + cb*64 + wn*32 + fn*16 + l15
    const unsigned short* B0 = Wn + (size_t)(cg * 2048 + wn * 32 + l15) * Dd + l4 * 8;
    const unsigned short* bp = B0 + 32;   // rolling prefetch ptr -> (cb=0, kk=1)
    short8 b0s[2], b1s[2];
    b0s[0] = *(const short8*)(B0);
    b1s[0] = *(const short8*)(B0 + 16 * Dd);

    unsigned int rkey[4][4];
#pragma unroll
    for (int fm = 0; fm < 4; ++fm)
#pragma unroll
        for (int r = 0; r < 4; ++r) rkey[fm][r] = 0u;

    unsigned int ibase = (unsigned)(wn * 32 + l15);

    for (int cb = 0; cb < 32; ++cb) {
        floatx4 acc[4][2];
#pragma unroll
        for (int fm = 0; fm < 4; ++fm) {
            acc[fm][0] = (floatx4)192.0f;
            acc[fm][1] = (floatx4)192.0f;
        }
#pragma unroll
        for (int kk = 0; kk < 8; ++kk) {
            int s = kk & 1;
            if (cb < 31 || kk < 7) {            // prefetch t+1 into other slot
                b0s[s ^ 1] = *(const short8*)(bp);
                b1s[s ^ 1] = *(const short8*)(bp + 4096);
                bp += (kk == 6) ? (16384 - 224) : 32;
            }
#pragma unroll
            for (int fm = 0; fm < 4; ++fm) {
                acc[fm][0] = __builtin_amdgcn_mfma_f32_16x16x32_bf16(af[fm][kk], b0s[s], acc[fm][0], 0, 0, 0);
                acc[fm][1] = __builtin_amdgcn_mfma_f32_16x16x32_bf16(af[fm][kk], b1s[s], acc[fm][1], 0, 0, 0);
            }
        }
        unsigned int i0 = (unsigned)(cb * 64) + ibase;
        unsigned int i1 = i0 + 16;
#pragma unroll
        for (int fm = 0; fm < 4; ++fm)
#pragma unroll
            for (int r = 0; r < 4; ++r) {
                unsigned int k0 = (__float_as_uint(acc[fm][0][r]) & 0xFFFFF000u) | i0;
                unsigned int k1 = (__float_as_uint(acc[fm][1][r]) & 0xFFFFF000u) | i1;
                unsigned int km = k0 > k1 ? k0 : k1;
                rkey[fm][r] = rkey[fm][r] > km ? rkey[fm][r] : km;
            }
    }

    // epilogue: u32-key max across the 16 column lanes, then across wn halves
#pragma unroll
    for (int fm = 0; fm < 4; ++fm)
#pragma unroll
        for (int r = 0; r < 4; ++r) {
            unsigned int kx = rkey[fm][r];
#pragma unroll
            for (int md = 1; md <= 8; md <<= 1) {
                unsigned int o = (unsigned int)__shfl_xor((int)kx, md, 64);
                kx = kx > o ? kx : o;
            }
            if (l15 == 0) red[wm * 64 + fm * 16 + l4 * 4 + r][wn] = kx;
        }
    __syncthreads();
    if (tid < 128) {
        unsigned int k0 = red[tid][0], k1 = red[tid][1];
        unsigned int kx = k0 > k1 ? k0 : k1;
        keys[(size_t)cg * Nn + bm * 128 + tid] = kx | ((unsigned)cg << 11);
    }
}

// ---------------------------------------------------------------- kernel 3
// final key-max over 2 col-groups + histogram + gather + loss accumulation
__global__ __launch_bounds__(256) void k_gather(
        const float* __restrict__ w, const float* __restrict__ x,
        const unsigned int* __restrict__ keys, float* __restrict__ out,
        float* __restrict__ lossacc, int* __restrict__ counts) {
    __shared__ float wt[128][258];
    __shared__ int kidx[128];
    int bid = blockIdx.x;
    int b = bid >> 5, l0 = (bid & 31) * 128;
    int tid = threadIdx.x;
    if (tid < 128) {
        int n = b * Ll + l0 + tid;
        unsigned int k0 = keys[n], k1 = keys[Nn + n];
        unsigned int kx = k0 > k1 ? k0 : k1;
        int ix = (int)(kx & 0xFFFu);
        kidx[tid] = ix;
        atomicAdd(&counts[ix], 1);
    }
    __syncthreads();
    {   // stage 128 selected codebook rows into LDS (2 threads/row)
        int r = tid >> 1, half = tid & 1;
        const float4* src = (const float4*)(w + (size_t)kidx[r] * Dd) + half * 32;
        float* dr = &wt[r][half * 128];
#pragma unroll
        for (int j = 0; j < 32; ++j) {
            float4 v = src[j];
            dr[j*4] = v.x; dr[j*4+1] = v.y; dr[j*4+2] = v.z; dr[j*4+3] = v.w;
        }
    }
    __syncthreads();
    // local LDS rows for the 4 consecutive l's this lane handles (FIX: local
    // row index, NOT the global codebook id)
    int lq = tid & 31, dg = tid >> 5;
    int r0 = lq * 4, r1 = r0 + 1, r2 = r0 + 2, r3 = r0 + 3;
    const float* xb = x + (size_t)b * Dd * Ll + l0 + lq * 4;
    float* ob = out + (size_t)b * Dd * Ll + l0 + lq * 4;
    float ls = 0.f;
    for (int d = dg; d < Dd; d += 8) {
        float4 xv = *(const float4*)(xb + (size_t)d * Ll);
        float4 qv = { wt[r0][d], wt[r1][d], wt[r2][d], wt[r3][d] };
        float d0 = qv.x - xv.x, d1 = qv.y - xv.y, d2 = qv.z - xv.z, d3 = qv.w - xv.w;
        ls += d0*d0 + d1*d1 + d2*d2 + d3*d3;
        *(float4*)(ob + (size_t)d * Ll) = qv;
    }
#pragma unroll
    for (int m = 1; m < 64; m <<= 1) ls += __shfl_xor(ls, m, 64);
    __shared__ float wsum[4];
    if ((tid & 63) == 0) wsum[tid >> 6] = ls;
    __syncthreads();
    if (tid == 0) atomicAdd(lossacc, wsum[0] + wsum[1] + wsum[2] + wsum[3]);
}

// ---------------------------------------------------------------- kernel 4
__global__ void k_final(const int* __restrict__ counts, const float* __restrict__ lossacc,
                        float* __restrict__ out) {
    int tid = threadIdx.x;
    float s = 0.f;
    for (int i = tid; i < Kk; i += 256) {
        float p = (float)counts[i] * (1.0f / Nn);
        s += p * logf(p + 1e-10f);
    }
#pragma unroll
    for (int m = 1; m < 64; m <<= 1) s += __shfl_xor(s, m, 64);
    __shared__ float ws_[4];
    if ((tid & 63) == 0) ws_[tid >> 6] = s;
    __syncthreads();
    if (tid == 0) {
        out[OUT0]     = lossacc[0] * 1.25f / (float)OUT0;   // q_latent + 0.25*e_latent
        out[OUT0 + 1] = expf(-(ws_[0] + ws_[1] + ws_[2] + ws_[3]));
    }
}

// ---------------------------------------------------------------- launch
extern "C" void kernel_launch(void* const* d_in, const int* in_sizes, int n_in,
                              void* d_out, int out_size, void* d_ws, size_t ws_size,
                              hipStream_t stream) {
    const float* x = (const float*)d_in[0];   // [B, D, L]
    const float* w = (const float*)d_in[1];   // [K, D]
    float* out = (float*)d_out;
    char* ws = (char*)d_ws;

    unsigned short* wn  = (unsigned short*)ws;                      //  2 MB
    unsigned short* A   = (unsigned short*)(ws + (2u  << 20));      // 16 MB
    unsigned int*  keys = (unsigned int*)(ws + (18u << 20));        // 256 KB
    int*   counts       = (int*)  (ws + (19u << 20));               // 16 KB + 4
    float* lossacc      = (float*)(counts + Kk);

    k_prep       <<<1536, 256, 0, stream>>>(x, w, A, wn, counts);
    k_gemm_argmax<<<512,  256, 0, stream>>>(A, wn, keys);
    k_gather     <<<256,  256, 0, stream>>>(w, x, keys, out, lossacc, counts);
    k_final      <<<1,    256, 0, stream>>>(counts, lossacc, out);
}

// Round 5
// 217.041 us; speedup vs baseline: 1.0960x; 1.0960x over previous
//
#include <hip/hip_runtime.h>
#include <stdint.h>

#define Bb 8
#define Dd 256
#define Ll 4096
#define Kk 4096
#define Nn (Bb * Ll)          // 32768 rows
#define OUT0 (Bb * Dd * Ll)   // 8388608

typedef int    int4v   __attribute__((ext_vector_type(4)));
typedef int    int8v   __attribute__((ext_vector_type(8)));
typedef float  floatx4 __attribute__((ext_vector_type(4)));

#define SCALE1 0x7F7F7F7F     // E8M0 exp=127 -> x1.0 for every 32-elem block

union V8 { int8v v; int4v h[2]; };

__device__ __forceinline__ void async_load16(const void* g, void* l) {
    __builtin_amdgcn_global_load_lds((const __attribute__((address_space(1))) void*)g,
                                     (__attribute__((address_space(3))) void*)l, 16, 0, 0);
}

// ---------------------------------------------------------------- kernel 1
// normalize codebook rows, scale x16, cast fp8 e4m3 (block 0 zeroes
// counts + lossacc + done). wn[k][d] = fp8(16 * w[k][d] / max(||w_k||,eps))
__global__ void k_prep(const float* __restrict__ w, unsigned char* __restrict__ wn,
                       int* __restrict__ counts) {
    int blk = blockIdx.x, tid = threadIdx.x;
    if (blk == 0)
        for (int i = tid; i < Kk + 2; i += 256) counts[i] = 0;
    int row  = blk * 4 + (tid >> 6);
    int lane = tid & 63;
    float4 v = ((const float4*)(w + (size_t)row * Dd))[lane];
    float ss = v.x*v.x + v.y*v.y + v.z*v.z + v.w*v.w;
#pragma unroll
    for (int m = 1; m < 64; m <<= 1) ss += __shfl_xor(ss, m, 64);
    float s = 16.0f / fmaxf(sqrtf(ss), 1e-12f);
    int p = __builtin_amdgcn_cvt_pk_fp8_f32(v.x * s, v.y * s, 0, false);
    p     = __builtin_amdgcn_cvt_pk_fp8_f32(v.z * s, v.w * s, p, true);
    ((int*)(wn + (size_t)row * Dd))[lane] = p;
}

// ---------------------------------------------------------------- kernel 2
// fused transpose + fp8 cast + argmax GEMM.
// Each block: rows bm*128..+128 (own x-slab, transposed into a 32KB LDS
// A-tile once), cols = cg half (2048), streamed as 32 cb-tiles of 64 cols
// through a 2x16KB LDS double buffer (global_load_lds, XOR-16B swizzle).
// MFMA: mfma_scale_f32_16x16x128_f8f6f4 (scale = 1.0). Packed-u32-key argmax.
__global__ __launch_bounds__(256, 2) void k_gemm_argmax(
        const float* __restrict__ x, const unsigned char* __restrict__ Wn,
        unsigned int* __restrict__ keys) {
    __shared__ __align__(16) unsigned char As[128 * 256];     // [l][d swz]
    __shared__ __align__(16) unsigned char Bs[2][64 * 256];   // [col][d swz]
    __shared__ unsigned int red[128][2];

    int blk = blockIdx.x;
    int cg = blk & 1, bm = blk >> 1;
    int tid = threadIdx.x, lane = tid & 63, w = tid >> 6;
    int wm = w >> 1, wn = w & 1;
    int l15 = lane & 15, l4 = lane >> 4;

    // B DMA maps: LDS slot q holds global 16B chunk (col=q>>4, c=(q&15)^(col&15))
    int goff[4], loff[4];
#pragma unroll
    for (int j = 0; j < 4; ++j) {
        int q = j * 256 + tid;
        int col = q >> 4, p = q & 15;
        goff[j] = col * 256 + ((p ^ (col & 15)) << 4);
        loff[j] = q * 16;
    }
    const unsigned char* Wg = Wn + (size_t)cg * 2048 * 256;

    // prologue DMA: col-block 0 -> Bs[0] (overlaps the transpose below)
#pragma unroll
    for (int j = 0; j < 4; ++j)
        async_load16(Wg + goff[j], (unsigned char*)Bs[0] + loff[j]);

    // ---- fused transpose: x slab [256 d][128 l] f32 -> As[l][d] fp8 (swz)
    int b = bm >> 5, l0 = (bm & 31) * 128;
    const float* xs = x + (size_t)b * Dd * Ll + l0;
    int lg = tid & 31, dgr = tid >> 5;
#pragma unroll
    for (int i = 0; i < 8; ++i) {
        int d0 = dgr * 4 + i * 32;
        const float* s0 = xs + (size_t)d0 * Ll + lg * 4;
        float4 f0 = *(const float4*)(s0);
        float4 f1 = *(const float4*)(s0 + Ll);
        float4 f2 = *(const float4*)(s0 + 2 * (size_t)Ll);
        float4 f3 = *(const float4*)(s0 + 3 * (size_t)Ll);
#pragma unroll
        for (int jl = 0; jl < 4; ++jl) {
            float a0 = ((const float*)&f0)[jl], a1 = ((const float*)&f1)[jl];
            float a2 = ((const float*)&f2)[jl], a3 = ((const float*)&f3)[jl];
            int pk = __builtin_amdgcn_cvt_pk_fp8_f32(a0, a1, 0, false);
            pk     = __builtin_amdgcn_cvt_pk_fp8_f32(a2, a3, pk, true);
            int l = lg * 4 + jl;
            *(int*)(As + l * 256 + (((d0 >> 4) ^ (l & 15)) << 4) + (d0 & 15)) = pk;
        }
    }
    __syncthreads();   // As complete + Bs[0] DMA drained

    // ---- A fragments (64 VGPRs): row = wm*64+fm*16+l15, k = ks*128+l4*32+byte
    int8v af[4][2];
#pragma unroll
    for (int fm = 0; fm < 4; ++fm)
#pragma unroll
        for (int ks = 0; ks < 2; ++ks) {
            int l = wm * 64 + fm * 16 + l15;
            int ch = ks * 8 + l4 * 2;
            V8 u;
            u.h[0] = *(const int4v*)(As + l * 256 + ((ch ^ l15) << 4));
            u.h[1] = *(const int4v*)(As + l * 256 + (((ch + 1) ^ l15) << 4));
            af[fm][ks] = u.v;
        }

    unsigned int rk[4][4];
#pragma unroll
    for (int fm = 0; fm < 4; ++fm)
#pragma unroll
        for (int r = 0; r < 4; ++r) rk[fm][r] = 0u;

    for (int cb = 0; cb < 32; ++cb) {
        int cur = cb & 1;
        if (cb < 31) {           // prefetch next tile into other buffer
            const unsigned char* g = Wg + (size_t)(cb + 1) * 64 * 256;
            unsigned char* lb = (unsigned char*)Bs[cur ^ 1];
#pragma unroll
            for (int j = 0; j < 4; ++j)
                async_load16(g + goff[j], lb + loff[j]);
        }
        const unsigned char* bb = (const unsigned char*)Bs[cur];
        int8v bf[2][2];
#pragma unroll
        for (int fn = 0; fn < 2; ++fn)
#pragma unroll
            for (int ks = 0; ks < 2; ++ks) {
                int col = wn * 32 + fn * 16 + l15;
                int ch = ks * 8 + l4 * 2;
                V8 u;
                u.h[0] = *(const int4v*)(bb + col * 256 + ((ch ^ l15) << 4));
                u.h[1] = *(const int4v*)(bb + col * 256 + (((ch + 1) ^ l15) << 4));
                bf[fn][ks] = u.v;
            }
        floatx4 acc[4][2];
#pragma unroll
        for (int fm = 0; fm < 4; ++fm)
#pragma unroll
            for (int fn = 0; fn < 2; ++fn) {
                floatx4 a = (floatx4)512.0f;    // bias -> positive one-sign range
                a = __builtin_amdgcn_mfma_scale_f32_16x16x128_f8f6f4(
                        af[fm][0], bf[fn][0], a, 0, 0, 0, SCALE1, 0, SCALE1);
                a = __builtin_amdgcn_mfma_scale_f32_16x16x128_f8f6f4(
                        af[fm][1], bf[fn][1], a, 0, 0, 0, SCALE1, 0, SCALE1);
                acc[fm][fn] = a;
            }
        unsigned int i0 = (unsigned)(cb * 64 + wn * 32 + l15);
#pragma unroll
        for (int fm = 0; fm < 4; ++fm)
#pragma unroll
            for (int r = 0; r < 4; ++r) {
                unsigned int k0 = (__float_as_uint(acc[fm][0][r]) & 0xFFFFF000u) | i0;
                unsigned int k1 = (__float_as_uint(acc[fm][1][r]) & 0xFFFFF000u) | (i0 + 16u);
                unsigned int km = k0 > k1 ? k0 : k1;
                rk[fm][r] = rk[fm][r] > km ? rk[fm][r] : km;
            }
        __syncthreads();         // guards buffer reuse + drains prefetch DMA
    }

    // epilogue: key-max across 16 col-lanes, then across wn halves
#pragma unroll
    for (int fm = 0; fm < 4; ++fm)
#pragma unroll
        for (int r = 0; r < 4; ++r) {
            unsigned int kx = rk[fm][r];
#pragma unroll
            for (int md = 1; md <= 8; md <<= 1) {
                unsigned int o = (unsigned int)__shfl_xor((int)kx, md, 64);
                kx = kx > o ? kx : o;
            }
            if (l15 == 0) red[wm * 64 + fm * 16 + l4 * 4 + r][wn] = kx;
        }
    __syncthreads();
    if (tid < 128) {
        unsigned int k0 = red[tid][0], k1 = red[tid][1];
        unsigned int kx = k0 > k1 ? k0 : k1;
        keys[(size_t)cg * Nn + bm * 128 + tid] = kx | ((unsigned)cg << 11);
    }
}

// ---------------------------------------------------------------- kernel 3
// key merge + histogram + gather + loss; last block computes loss/perplexity.
// grid = 2048 x 64thr: dp = blk>>9 selects a 64-d quarter, n = (blk&511)*64+lane.
__global__ __launch_bounds__(64) void k_gather(
        const float* __restrict__ w, const float* __restrict__ x,
        const unsigned int* __restrict__ keys, float* __restrict__ out,
        int* __restrict__ counts) {
    float* lossacc = (float*)(counts + Kk);
    int*   done    = counts + Kk + 1;
    int blk = blockIdx.x, lane = threadIdx.x;
    int dp = blk >> 9;
    int n  = (blk & 511) * 64 + lane;
    unsigned int k0 = keys[n], k1 = keys[Nn + n];
    unsigned int kx = k0 > k1 ? k0 : k1;
    int ix = (int)(kx & 0xFFFu);
    if (dp == 0) atomicAdd(&counts[ix], 1);
    int b = n >> 12, l = n & (Ll - 1);
    const float* xb = x + (size_t)b * Dd * Ll + l;
    float* ob = out + (size_t)b * Dd * Ll + l;
    const float4* wr = (const float4*)(w + (size_t)ix * Dd);
    float ls = 0.f;
#pragma unroll 4
    for (int dq = 0; dq < 16; ++dq) {
        float4 q = wr[dp * 16 + dq];
#pragma unroll
        for (int j = 0; j < 4; ++j) {
            int d = dp * 64 + dq * 4 + j;
            float qv = ((const float*)&q)[j];
            float xv = xb[(size_t)d * Ll];
            float df = qv - xv;
            ls += df * df;
            ob[(size_t)d * Ll] = qv;
        }
    }
#pragma unroll
    for (int m = 1; m < 64; m <<= 1) ls += __shfl_xor(ls, m, 64);
    int last = 0;
    if (lane == 0) {
        atomicAdd(lossacc, ls);
        __threadfence();
        last = (atomicAdd(done, 1) == 2047);
    }
    last = __shfl(last, 0);
    if (last) {                  // all counts/loss atomics are globally visible
        __threadfence();
        float s = 0.f;
        for (int i = lane; i < Kk; i += 64) {
            float p = (float)counts[i] * (1.0f / Nn);
            s += p * logf(p + 1e-10f);
        }
#pragma unroll
        for (int m = 1; m < 64; m <<= 1) s += __shfl_xor(s, m, 64);
        if (lane == 0) {
            out[OUT0]     = lossacc[0] * 1.25f / (float)OUT0;  // q + 0.25*e latent
            out[OUT0 + 1] = expf(-s);
        }
    }
}

// ---------------------------------------------------------------- launch
extern "C" void kernel_launch(void* const* d_in, const int* in_sizes, int n_in,
                              void* d_out, int out_size, void* d_ws, size_t ws_size,
                              hipStream_t stream) {
    const float* x = (const float*)d_in[0];   // [B, D, L]
    const float* w = (const float*)d_in[1];   // [K, D]
    float* out = (float*)d_out;
    char* ws = (char*)d_ws;

    unsigned char* wn   = (unsigned char*)ws;                         // 1 MB fp8
    unsigned int*  keys = (unsigned int*)(ws + (1u << 20));           // 256 KB
    int*           counts = (int*)(ws + (1u << 20) + (256u << 10));   // 16 KB + 8

    k_prep       <<<1024, 256, 0, stream>>>(w, wn, counts);
    k_gemm_argmax<<<512,  256, 0, stream>>>(x, wn, keys);
    k_gather     <<<2048,  64, 0, stream>>>(w, x, keys, out, counts);
}

// Round 6
// 180.272 us; speedup vs baseline: 1.3196x; 1.2040x over previous
//
#include <hip/hip_runtime.h>
#include <stdint.h>

#define Bb 8
#define Dd 256
#define Ll 4096
#define Kk 4096
#define Nn (Bb * Ll)          // 32768 rows
#define OUT0 (Bb * Dd * Ll)   // 8388608

typedef int    int4v   __attribute__((ext_vector_type(4)));
typedef int    int8v   __attribute__((ext_vector_type(8)));
typedef float  floatx4 __attribute__((ext_vector_type(4)));

#define SCALE1 0x7F7F7F7F     // E8M0 exp=127 -> x1.0 for every 32-elem block

union V8 { int8v v; int4v h[2]; };

__device__ __forceinline__ void async_load16(const void* g, void* l) {
    __builtin_amdgcn_global_load_lds((const __attribute__((address_space(1))) void*)g,
                                     (__attribute__((address_space(3))) void*)l, 16, 0, 0);
}

// ---------------------------------------------------------------- kernel 1
// normalize codebook rows, scale x16, cast fp8 e4m3 (block 0 zeroes
// counts + lossacc + done). wn[k][d] = fp8(16 * w[k][d] / max(||w_k||,eps))
__global__ void k_prep(const float* __restrict__ w, unsigned char* __restrict__ wn,
                       int* __restrict__ counts) {
    int blk = blockIdx.x, tid = threadIdx.x;
    if (blk == 0)
        for (int i = tid; i < Kk + 2; i += 256) counts[i] = 0;
    int row  = blk * 4 + (tid >> 6);
    int lane = tid & 63;
    float4 v = ((const float4*)(w + (size_t)row * Dd))[lane];
    float ss = v.x*v.x + v.y*v.y + v.z*v.z + v.w*v.w;
#pragma unroll
    for (int m = 1; m < 64; m <<= 1) ss += __shfl_xor(ss, m, 64);
    float s = 16.0f / fmaxf(sqrtf(ss), 1e-12f);
    int p = __builtin_amdgcn_cvt_pk_fp8_f32(v.x * s, v.y * s, 0, false);
    p     = __builtin_amdgcn_cvt_pk_fp8_f32(v.z * s, v.w * s, p, true);
    ((int*)(wn + (size_t)row * Dd))[lane] = p;
}

// ---------------------------------------------------------------- kernel 2
// fused transpose + fp8 cast + argmax GEMM. (unchanged from R5)
__global__ __launch_bounds__(256, 2) void k_gemm_argmax(
        const float* __restrict__ x, const unsigned char* __restrict__ Wn,
        unsigned int* __restrict__ keys) {
    __shared__ __align__(16) unsigned char As[128 * 256];     // [l][d swz]
    __shared__ __align__(16) unsigned char Bs[2][64 * 256];   // [col][d swz]
    __shared__ unsigned int red[128][2];

    int blk = blockIdx.x;
    int cg = blk & 1, bm = blk >> 1;
    int tid = threadIdx.x, lane = tid & 63, w = tid >> 6;
    int wm = w >> 1, wn = w & 1;
    int l15 = lane & 15, l4 = lane >> 4;

    // B DMA maps: LDS slot q holds global 16B chunk (col=q>>4, c=(q&15)^(col&15))
    int goff[4], loff[4];
#pragma unroll
    for (int j = 0; j < 4; ++j) {
        int q = j * 256 + tid;
        int col = q >> 4, p = q & 15;
        goff[j] = col * 256 + ((p ^ (col & 15)) << 4);
        loff[j] = q * 16;
    }
    const unsigned char* Wg = Wn + (size_t)cg * 2048 * 256;

    // prologue DMA: col-block 0 -> Bs[0] (overlaps the transpose below)
#pragma unroll
    for (int j = 0; j < 4; ++j)
        async_load16(Wg + goff[j], (unsigned char*)Bs[0] + loff[j]);

    // ---- fused transpose: x slab [256 d][128 l] f32 -> As[l][d] fp8 (swz)
    int b = bm >> 5, l0 = (bm & 31) * 128;
    const float* xs = x + (size_t)b * Dd * Ll + l0;
    int lg = tid & 31, dgr = tid >> 5;
#pragma unroll
    for (int i = 0; i < 8; ++i) {
        int d0 = dgr * 4 + i * 32;
        const float* s0 = xs + (size_t)d0 * Ll + lg * 4;
        float4 f0 = *(const float4*)(s0);
        float4 f1 = *(const float4*)(s0 + Ll);
        float4 f2 = *(const float4*)(s0 + 2 * (size_t)Ll);
        float4 f3 = *(const float4*)(s0 + 3 * (size_t)Ll);
#pragma unroll
        for (int jl = 0; jl < 4; ++jl) {
            float a0 = ((const float*)&f0)[jl], a1 = ((const float*)&f1)[jl];
            float a2 = ((const float*)&f2)[jl], a3 = ((const float*)&f3)[jl];
            int pk = __builtin_amdgcn_cvt_pk_fp8_f32(a0, a1, 0, false);
            pk     = __builtin_amdgcn_cvt_pk_fp8_f32(a2, a3, pk, true);
            int l = lg * 4 + jl;
            *(int*)(As + l * 256 + (((d0 >> 4) ^ (l & 15)) << 4) + (d0 & 15)) = pk;
        }
    }
    __syncthreads();   // As complete + Bs[0] DMA drained

    // ---- A fragments (64 VGPRs): row = wm*64+fm*16+l15, k = ks*128+l4*32+byte
    int8v af[4][2];
#pragma unroll
    for (int fm = 0; fm < 4; ++fm)
#pragma unroll
        for (int ks = 0; ks < 2; ++ks) {
            int l = wm * 64 + fm * 16 + l15;
            int ch = ks * 8 + l4 * 2;
            V8 u;
            u.h[0] = *(const int4v*)(As + l * 256 + ((ch ^ l15) << 4));
            u.h[1] = *(const int4v*)(As + l * 256 + (((ch + 1) ^ l15) << 4));
            af[fm][ks] = u.v;
        }

    unsigned int rk[4][4];
#pragma unroll
    for (int fm = 0; fm < 4; ++fm)
#pragma unroll
        for (int r = 0; r < 4; ++r) rk[fm][r] = 0u;

    for (int cb = 0; cb < 32; ++cb) {
        int cur = cb & 1;
        if (cb < 31) {           // prefetch next tile into other buffer
            const unsigned char* g = Wg + (size_t)(cb + 1) * 64 * 256;
            unsigned char* lb = (unsigned char*)Bs[cur ^ 1];
#pragma unroll
            for (int j = 0; j < 4; ++j)
                async_load16(g + goff[j], lb + loff[j]);
        }
        const unsigned char* bb = (const unsigned char*)Bs[cur];
        int8v bf[2][2];
#pragma unroll
        for (int fn = 0; fn < 2; ++fn)
#pragma unroll
            for (int ks = 0; ks < 2; ++ks) {
                int col = wn * 32 + fn * 16 + l15;
                int ch = ks * 8 + l4 * 2;
                V8 u;
                u.h[0] = *(const int4v*)(bb + col * 256 + ((ch ^ l15) << 4));
                u.h[1] = *(const int4v*)(bb + col * 256 + (((ch + 1) ^ l15) << 4));
                bf[fn][ks] = u.v;
            }
        floatx4 acc[4][2];
#pragma unroll
        for (int fm = 0; fm < 4; ++fm)
#pragma unroll
            for (int fn = 0; fn < 2; ++fn) {
                floatx4 a = (floatx4)512.0f;    // bias -> positive one-sign range
                a = __builtin_amdgcn_mfma_scale_f32_16x16x128_f8f6f4(
                        af[fm][0], bf[fn][0], a, 0, 0, 0, SCALE1, 0, SCALE1);
                a = __builtin_amdgcn_mfma_scale_f32_16x16x128_f8f6f4(
                        af[fm][1], bf[fn][1], a, 0, 0, 0, SCALE1, 0, SCALE1);
                acc[fm][fn] = a;
            }
        unsigned int i0 = (unsigned)(cb * 64 + wn * 32 + l15);
#pragma unroll
        for (int fm = 0; fm < 4; ++fm)
#pragma unroll
            for (int r = 0; r < 4; ++r) {
                unsigned int k0 = (__float_as_uint(acc[fm][0][r]) & 0xFFFFF000u) | i0;
                unsigned int k1 = (__float_as_uint(acc[fm][1][r]) & 0xFFFFF000u) | (i0 + 16u);
                unsigned int km = k0 > k1 ? k0 : k1;
                rk[fm][r] = rk[fm][r] > km ? rk[fm][r] : km;
            }
        __syncthreads();         // guards buffer reuse + drains prefetch DMA
    }

    // epilogue: key-max across 16 col-lanes, then across wn halves
#pragma unroll
    for (int fm = 0; fm < 4; ++fm)
#pragma unroll
        for (int r = 0; r < 4; ++r) {
            unsigned int kx = rk[fm][r];
#pragma unroll
            for (int md = 1; md <= 8; md <<= 1) {
                unsigned int o = (unsigned int)__shfl_xor((int)kx, md, 64);
                kx = kx > o ? kx : o;
            }
            if (l15 == 0) red[wm * 64 + fm * 16 + l4 * 4 + r][wn] = kx;
        }
    __syncthreads();
    if (tid < 128) {
        unsigned int k0 = red[tid][0], k1 = red[tid][1];
        unsigned int kx = k0 > k1 ? k0 : k1;
        keys[(size_t)cg * Nn + bm * 128 + tid] = kx | ((unsigned)cg << 11);
    }
}

// ---------------------------------------------------------------- kernel 3
// key merge + histogram + gather + loss; coalesced rewrite:
// 1024 blocks x 256 thr, 32 l's per block. w rows staged in LDS (one 1KB
// coalesced wave-instruction per row); x/out moved as float4 along l
// (128B granules). Last block computes loss + perplexity.
__global__ __launch_bounds__(256) void k_gather(
        const float* __restrict__ w, const float* __restrict__ x,
        const unsigned int* __restrict__ keys, float* __restrict__ out,
        int* __restrict__ counts) {
    __shared__ float wt[32][260];     // row stride 260: 16B-aligned, odd/4 banks
    __shared__ int kidx[32];
    __shared__ float wsum[4];
    __shared__ int lastsh;
    float* lossacc = (float*)(counts + Kk);
    int*   done    = counts + Kk + 1;

    int blk = blockIdx.x, tid = threadIdx.x;
    int n0 = blk * 32;
    if (tid < 32) {
        unsigned int k0 = keys[n0 + tid], k1 = keys[Nn + n0 + tid];
        unsigned int kx = k0 > k1 ? k0 : k1;
        int ix = (int)(kx & 0xFFFu);
        kidx[tid] = ix;
        atomicAdd(&counts[ix], 1);
    }
    __syncthreads();
    int lane = tid & 63, wv = tid >> 6;
#pragma unroll
    for (int r8 = 0; r8 < 8; ++r8) {          // wave wv stages rows wv*8..+8
        int r = wv * 8 + r8;
        float4 v = *(const float4*)(w + (size_t)kidx[r] * Dd + lane * 4);
        *(float4*)(&wt[r][lane * 4]) = v;
    }
    __syncthreads();

    int lq = tid & 7, dg = tid >> 3;          // 8 l-groups x 32 d-groups
    int b = n0 >> 12, l0 = n0 & (Ll - 1);
    const float* xp = x   + (size_t)b * Dd * Ll + l0 + lq * 4;
    float*       op = out + (size_t)b * Dd * Ll + l0 + lq * 4;
    int r0 = lq * 4;
    float ls = 0.f;
#pragma unroll
    for (int i = 0; i < 8; ++i) {
        int d = i * 32 + dg;
        float4 xv = *(const float4*)(xp + (size_t)d * Ll);
        float4 qv = { wt[r0][d], wt[r0 + 1][d], wt[r0 + 2][d], wt[r0 + 3][d] };
        float d0 = qv.x - xv.x, d1 = qv.y - xv.y, d2 = qv.z - xv.z, d3 = qv.w - xv.w;
        ls += d0*d0 + d1*d1 + d2*d2 + d3*d3;
        *(float4*)(op + (size_t)d * Ll) = qv;
    }
#pragma unroll
    for (int m = 1; m < 64; m <<= 1) ls += __shfl_xor(ls, m, 64);
    if (lane == 0) wsum[wv] = ls;
    __syncthreads();
    if (tid == 0) {
        atomicAdd(lossacc, wsum[0] + wsum[1] + wsum[2] + wsum[3]);
        __threadfence();
        lastsh = (atomicAdd(done, 1) == 1023);
    }
    __syncthreads();
    if (lastsh) {                 // all blocks' counts/loss atomics now visible
        __threadfence();
        float s = 0.f;
        for (int i = tid; i < Kk; i += 256) {
            float p = (float)counts[i] * (1.0f / Nn);
            s += p * logf(p + 1e-10f);
        }
#pragma unroll
        for (int m = 1; m < 64; m <<= 1) s += __shfl_xor(s, m, 64);
        if (lane == 0) wsum[wv] = s;
        __syncthreads();
        if (tid == 0) {
            out[OUT0]     = lossacc[0] * 1.25f / (float)OUT0;  // q + 0.25*e latent
            out[OUT0 + 1] = expf(-(wsum[0] + wsum[1] + wsum[2] + wsum[3]));
        }
    }
}

// ---------------------------------------------------------------- launch
extern "C" void kernel_launch(void* const* d_in, const int* in_sizes, int n_in,
                              void* d_out, int out_size, void* d_ws, size_t ws_size,
                              hipStream_t stream) {
    const float* x = (const float*)d_in[0];   // [B, D, L]
    const float* w = (const float*)d_in[1];   // [K, D]
    float* out = (float*)d_out;
    char* ws = (char*)d_ws;

    unsigned char* wn   = (unsigned char*)ws;                         // 1 MB fp8
    unsigned int*  keys = (unsigned int*)(ws + (1u << 20));           // 256 KB
    int*           counts = (int*)(ws + (1u << 20) + (256u << 10));   // 16 KB + 8

    k_prep       <<<1024, 256, 0, stream>>>(w, wn, counts);
    k_gemm_argmax<<<512,  256, 0, stream>>>(x, wn, keys);
    k_gather     <<<1024, 256, 0, stream>>>(w, x, keys, out, counts);
}

// Round 7
// 174.365 us; speedup vs baseline: 1.3643x; 1.0339x over previous
//
#include <hip/hip_runtime.h>
#include <stdint.h>

#define Bb 8
#define Dd 256
#define Ll 4096
#define Kk 4096
#define Nn (Bb * Ll)          // 32768 rows
#define OUT0 (Bb * Dd * Ll)   // 8388608

typedef int    int4v   __attribute__((ext_vector_type(4)));
typedef int    int8v   __attribute__((ext_vector_type(8)));
typedef float  floatx4 __attribute__((ext_vector_type(4)));

#define SCALE1 0x7F7F7F7F     // E8M0 exp=127 -> x1.0 for every 32-elem block

union V8 { int8v v; int4v h[2]; };

__device__ __forceinline__ void async_load16(const void* g, void* l) {
    __builtin_amdgcn_global_load_lds((const __attribute__((address_space(1))) void*)g,
                                     (__attribute__((address_space(3))) void*)l, 16, 0, 0);
}

// ---------------------------------------------------------------- kernel 1
// normalize codebook rows, scale x16, cast fp8 e4m3 (block 0 zeroes
// counts + lossacc + done). wn[k][d] = fp8(16 * w[k][d] / max(||w_k||,eps))
__global__ void k_prep(const float* __restrict__ w, unsigned char* __restrict__ wn,
                       int* __restrict__ counts) {
    int blk = blockIdx.x, tid = threadIdx.x;
    if (blk == 0)
        for (int i = tid; i < Kk + 2; i += 256) counts[i] = 0;
    int row  = blk * 4 + (tid >> 6);
    int lane = tid & 63;
    float4 v = ((const float4*)(w + (size_t)row * Dd))[lane];
    float ss = v.x*v.x + v.y*v.y + v.z*v.z + v.w*v.w;
#pragma unroll
    for (int m = 1; m < 64; m <<= 1) ss += __shfl_xor(ss, m, 64);
    float s = 16.0f / fmaxf(sqrtf(ss), 1e-12f);
    int p = __builtin_amdgcn_cvt_pk_fp8_f32(v.x * s, v.y * s, 0, false);
    p     = __builtin_amdgcn_cvt_pk_fp8_f32(v.z * s, v.w * s, p, true);
    ((int*)(wn + (size_t)row * Dd))[lane] = p;
}

// ---------------------------------------------------------------- kernel 2
// fused transpose + fp8 cast + full-col argmax GEMM.
// 256 blocks x 512 thr: block owns 128 rows x ALL 4096 cols (32 cb-tiles of
// 128 cols through a 2x32KB LDS double buffer). Wave tile 64r x 32c
// (wm=w>>2, wn=w&3). Writes final idx directly (no cross-block merge).
// launch_bounds(512,2) -> 256-VGPR cap (af 64 + acc 32 + bf 32 fit, no spill).
__global__ __launch_bounds__(512, 2) void k_gemm_argmax(
        const float* __restrict__ x, const unsigned char* __restrict__ Wn,
        int* __restrict__ idxout) {
    __shared__ __align__(16) unsigned char As[128 * 256];     // 32 KB [l][d swz]
    __shared__ __align__(16) unsigned char Bs[2][128 * 256];  // 2 x 32 KB
    __shared__ unsigned int red[128][4];

    int bm = blockIdx.x;
    int tid = threadIdx.x, lane = tid & 63, w = tid >> 6;
    int wm = w >> 2, wn = w & 3;
    int l15 = lane & 15, l4 = lane >> 4;

    // B DMA maps: LDS slot q holds global 16B chunk (col=q>>4, c=(q&15)^(col&15))
    int goff[4], loff[4];
#pragma unroll
    for (int j = 0; j < 4; ++j) {
        int q = j * 512 + tid;            // 0..2047 chunks = 128 cols x 256 B
        int col = q >> 4, p = q & 15;
        goff[j] = col * 256 + ((p ^ (col & 15)) << 4);
        loff[j] = q * 16;
    }

    // prologue DMA: col-tile 0 -> Bs[0] (overlaps transpose below)
#pragma unroll
    for (int j = 0; j < 4; ++j)
        async_load16(Wn + goff[j], (unsigned char*)Bs[0] + loff[j]);

    // ---- fused transpose: x slab [256 d][128 l] f32 -> As[l][d] fp8 (swz)
    int b = bm >> 5, l0 = (bm & 31) * 128;
    const float* xs = x + (size_t)b * Dd * Ll + l0;
    int lg = tid & 31, dgr = tid >> 5;    // 32 l-groups x 16 d-groups
#pragma unroll
    for (int i = 0; i < 4; ++i) {
        int d0 = dgr * 4 + i * 64;
        const float* s0 = xs + (size_t)d0 * Ll + lg * 4;
        float4 f0 = *(const float4*)(s0);
        float4 f1 = *(const float4*)(s0 + Ll);
        float4 f2 = *(const float4*)(s0 + 2 * (size_t)Ll);
        float4 f3 = *(const float4*)(s0 + 3 * (size_t)Ll);
#pragma unroll
        for (int jl = 0; jl < 4; ++jl) {
            float a0 = ((const float*)&f0)[jl], a1 = ((const float*)&f1)[jl];
            float a2 = ((const float*)&f2)[jl], a3 = ((const float*)&f3)[jl];
            int pk = __builtin_amdgcn_cvt_pk_fp8_f32(a0, a1, 0, false);
            pk     = __builtin_amdgcn_cvt_pk_fp8_f32(a2, a3, pk, true);
            int l = lg * 4 + jl;
            *(int*)(As + l * 256 + (((d0 >> 4) ^ (l & 15)) << 4) + (d0 & 15)) = pk;
        }
    }
    __syncthreads();   // As complete + Bs[0] DMA drained

    // ---- A fragments (64 VGPRs): row = wm*64+fm*16+l15, k = ks*128+l4*32
    int8v af[4][2];
#pragma unroll
    for (int fm = 0; fm < 4; ++fm)
#pragma unroll
        for (int ks = 0; ks < 2; ++ks) {
            int l = wm * 64 + fm * 16 + l15;
            int ch = ks * 8 + l4 * 2;
            V8 u;
            u.h[0] = *(const int4v*)(As + l * 256 + ((ch ^ l15) << 4));
            u.h[1] = *(const int4v*)(As + l * 256 + (((ch + 1) ^ l15) << 4));
            af[fm][ks] = u.v;
        }

    unsigned int rk[4][4];
#pragma unroll
    for (int fm = 0; fm < 4; ++fm)
#pragma unroll
        for (int r = 0; r < 4; ++r) rk[fm][r] = 0u;

    for (int cb = 0; cb < 32; ++cb) {
        int cur = cb & 1;
        if (cb < 31) {           // prefetch next 128-col tile into other buffer
            const unsigned char* g = Wn + (size_t)(cb + 1) * 128 * 256;
            unsigned char* lb = (unsigned char*)Bs[cur ^ 1];
#pragma unroll
            for (int j = 0; j < 4; ++j)
                async_load16(g + goff[j], lb + loff[j]);
        }
        const unsigned char* bb = (const unsigned char*)Bs[cur];
        int8v bf[2][2];
#pragma unroll
        for (int fn = 0; fn < 2; ++fn)
#pragma unroll
            for (int ks = 0; ks < 2; ++ks) {
                int col = wn * 32 + fn * 16 + l15;     // 0..127
                int ch = ks * 8 + l4 * 2;
                V8 u;
                u.h[0] = *(const int4v*)(bb + col * 256 + ((ch ^ l15) << 4));
                u.h[1] = *(const int4v*)(bb + col * 256 + (((ch + 1) ^ l15) << 4));
                bf[fn][ks] = u.v;
            }
        floatx4 acc[4][2];
#pragma unroll
        for (int fm = 0; fm < 4; ++fm)
#pragma unroll
            for (int fn = 0; fn < 2; ++fn) {
                floatx4 a = (floatx4)512.0f;    // bias -> positive, int-ordered
                a = __builtin_amdgcn_mfma_scale_f32_16x16x128_f8f6f4(
                        af[fm][0], bf[fn][0], a, 0, 0, 0, SCALE1, 0, SCALE1);
                a = __builtin_amdgcn_mfma_scale_f32_16x16x128_f8f6f4(
                        af[fm][1], bf[fn][1], a, 0, 0, 0, SCALE1, 0, SCALE1);
                acc[fm][fn] = a;
            }
        unsigned int i0 = (unsigned)(cb * 128 + wn * 32 + l15);
#pragma unroll
        for (int fm = 0; fm < 4; ++fm)
#pragma unroll
            for (int r = 0; r < 4; ++r) {
                unsigned int k0 = (__float_as_uint(acc[fm][0][r]) & 0xFFFFF000u) | i0;
                unsigned int k1 = (__float_as_uint(acc[fm][1][r]) & 0xFFFFF000u) | (i0 + 16u);
                unsigned int km = k0 > k1 ? k0 : k1;
                rk[fm][r] = rk[fm][r] > km ? rk[fm][r] : km;
            }
        __syncthreads();         // guards buffer reuse + drains prefetch DMA
    }

    // epilogue: key-max across 16 col-lanes, then across 4 col-strips
#pragma unroll
    for (int fm = 0; fm < 4; ++fm)
#pragma unroll
        for (int r = 0; r < 4; ++r) {
            unsigned int kx = rk[fm][r];
#pragma unroll
            for (int md = 1; md <= 8; md <<= 1) {
                unsigned int o = (unsigned int)__shfl_xor((int)kx, md, 64);
                kx = kx > o ? kx : o;
            }
            if (l15 == 0) red[wm * 64 + fm * 16 + l4 * 4 + r][wn] = kx;
        }
    __syncthreads();
    if (tid < 128) {
        unsigned int k0 = red[tid][0], k1 = red[tid][1];
        unsigned int k2 = red[tid][2], k3 = red[tid][3];
        unsigned int kx = k0 > k1 ? k0 : k1;
        kx = kx > k2 ? kx : k2;
        kx = kx > k3 ? kx : k3;
        idxout[bm * 128 + tid] = (int)(kx & 0xFFFu);
    }
}

// ---------------------------------------------------------------- kernel 3
// histogram + gather + loss. Block = 128 l x 64 d (dq quarter); grid 256x4.
// w rows staged coalesced into stride-65 LDS; x/out moved as float4 along l
// (512 B segments). Last block computes loss + perplexity.
__global__ __launch_bounds__(256) void k_gather(
        const float* __restrict__ w, const float* __restrict__ x,
        const int* __restrict__ idx, float* __restrict__ out,
        int* __restrict__ counts) {
    __shared__ float wt[128 * 65];    // stride 65: stage 2-way (free), read 4-way
    __shared__ int kidx[128];
    __shared__ float wsum[4];
    __shared__ int lastsh;
    float* lossacc = (float*)(counts + Kk);
    int*   done    = counts + Kk + 1;

    int blk = blockIdx.x, tid = threadIdx.x;
    int dq = blk & 3, lb = blk >> 2;
    int n0 = lb * 128;
    if (tid < 128) {
        int ix = idx[n0 + tid];
        kidx[tid] = ix;
        if (dq == 0) atomicAdd(&counts[ix], 1);
    }
    __syncthreads();
    int lane = tid & 63, wv = tid >> 6;
    {   // stage 128 rows x 64 d quarter: 4 rows per wave-instr, 256 B/row
        int rr = lane >> 4, c16 = lane & 15;
#pragma unroll
        for (int jr = 0; jr < 8; ++jr) {
            int r = wv * 32 + jr * 4 + rr;
            float4 v = *(const float4*)(w + (size_t)kidx[r] * Dd + dq * 64 + c16 * 4);
            float* dst = &wt[r * 65 + c16 * 4];
            dst[0] = v.x; dst[1] = v.y; dst[2] = v.z; dst[3] = v.w;
        }
    }
    __syncthreads();

    int lq = tid & 31, dg = tid >> 5;         // 32 l-quads x 8 d-groups
    int b = n0 >> 12, l0 = n0 & (Ll - 1);
    const float* xp = x   + ((size_t)b * Dd + dq * 64) * Ll + l0 + lq * 4;
    float*       op = out + ((size_t)b * Dd + dq * 64) * Ll + l0 + lq * 4;
    int r0 = lq * 4;
    float ls = 0.f;
#pragma unroll
    for (int i = 0; i < 8; ++i) {
        int d = i * 8 + dg;
        float4 xv = *(const float4*)(xp + (size_t)d * Ll);
        float4 qv = { wt[r0 * 65 + d],       wt[(r0 + 1) * 65 + d],
                      wt[(r0 + 2) * 65 + d], wt[(r0 + 3) * 65 + d] };
        float d0 = qv.x - xv.x, d1 = qv.y - xv.y, d2 = qv.z - xv.z, d3 = qv.w - xv.w;
        ls += d0*d0 + d1*d1 + d2*d2 + d3*d3;
        *(float4*)(op + (size_t)d * Ll) = qv;
    }
#pragma unroll
    for (int m = 1; m < 64; m <<= 1) ls += __shfl_xor(ls, m, 64);
    if (lane == 0) wsum[wv] = ls;
    __syncthreads();
    if (tid == 0) {
        atomicAdd(lossacc, wsum[0] + wsum[1] + wsum[2] + wsum[3]);
        __threadfence();
        lastsh = (atomicAdd(done, 1) == 1023);
    }
    __syncthreads();
    if (lastsh) {                 // all blocks' counts/loss atomics now visible
        __threadfence();
        float s = 0.f;
        for (int i = tid; i < Kk; i += 256) {
            float p = (float)counts[i] * (1.0f / Nn);
            s += p * logf(p + 1e-10f);
        }
#pragma unroll
        for (int m = 1; m < 64; m <<= 1) s += __shfl_xor(s, m, 64);
        if (lane == 0) wsum[wv] = s;
        __syncthreads();
        if (tid == 0) {
            out[OUT0]     = lossacc[0] * 1.25f / (float)OUT0;  // q + 0.25*e latent
            out[OUT0 + 1] = expf(-(wsum[0] + wsum[1] + wsum[2] + wsum[3]));
        }
    }
}

// ---------------------------------------------------------------- launch
extern "C" void kernel_launch(void* const* d_in, const int* in_sizes, int n_in,
                              void* d_out, int out_size, void* d_ws, size_t ws_size,
                              hipStream_t stream) {
    const float* x = (const float*)d_in[0];   // [B, D, L]
    const float* w = (const float*)d_in[1];   // [K, D]
    float* out = (float*)d_out;
    char* ws = (char*)d_ws;

    unsigned char* wn   = (unsigned char*)ws;                         // 1 MB fp8
    int*           idx  = (int*)(ws + (1u << 20));                    // 128 KB
    int*           counts = (int*)(ws + (1u << 20) + (128u << 10));   // 16 KB + 8

    k_prep       <<<1024, 256, 0, stream>>>(w, wn, counts);
    k_gemm_argmax<<<256,  512, 0, stream>>>(x, wn, idx);
    k_gather     <<<1024, 256, 0, stream>>>(w, x, idx, out, counts);
}